// Round 1
// baseline (156.776 us; speedup 1.0000x reference)
//
#include <hip/hip_runtime.h>
#include <math.h>

constexpr int Bn = 8, Cn = 512, Sn = 256, Mn = 200, Ln = 100;

// workspace layout (in floats)
constexpr size_t OFF_V    = 0;                                // [B*C*S]  = 1,048,576
constexpr size_t OFF_A    = OFF_V   + (size_t)Bn*Cn*Sn;       // [B*M*C]  =   819,200
constexpr size_t OFF_Z    = OFF_A   + (size_t)Bn*Mn*Cn;       // [B*M*S]  =   409,600
constexpr size_t OFF_INV  = OFF_Z   + (size_t)Bn*Mn*Sn;       // [B*M]
constexpr size_t OFF_ZW   = OFF_INV + (size_t)Bn*Mn;          // [B*M]
constexpr size_t OFF_ZPW  = OFF_ZW  + (size_t)Bn*Mn;          // [B*M]
constexpr size_t OFF_WSUM = OFF_ZPW + (size_t)Bn*Mn;          // [S]

// ---------- block-wide reductions (blockDim == 256 always) ----------
__device__ __forceinline__ float blk_max(float x, float* red) {
  #pragma unroll
  for (int o = 32; o; o >>= 1) x = fmaxf(x, __shfl_xor(x, o));
  __syncthreads();                      // protect red reuse across calls
  if ((threadIdx.x & 63) == 0) red[threadIdx.x >> 6] = x;
  __syncthreads();
  return fmaxf(fmaxf(red[0], red[1]), fmaxf(red[2], red[3]));
}
__device__ __forceinline__ float blk_sum(float x, float* red) {
  #pragma unroll
  for (int o = 32; o; o >>= 1) x += __shfl_xor(x, o);
  __syncthreads();
  if ((threadIdx.x & 63) == 0) red[threadIdx.x >> 6] = x;
  __syncthreads();
  return red[0] + red[1] + red[2] + red[3];
}

// ---------- wsum[s] = sum_t out_w[s,t] ----------
__global__ void k_wsum(const float* __restrict__ w, float* __restrict__ ws) {
  int t = threadIdx.x;
  const float* row = w + (size_t)t * Sn;
  float s = 0.f;
  for (int j = 0; j < Sn; j += 4) {
    float4 f = *(const float4*)(row + j);
    s += f.x + f.y + f.z + f.w;
  }
  ws[OFF_WSUM + t] = s;
}

// ---------- 8x8 block-mean pool: x[b,c,128,128] -> v[b,c,256] ----------
__global__ void __launch_bounds__(256) k_pool(const float* __restrict__ x,
                                              float* __restrict__ ws) {
  int bc = blockIdx.x;                       // (b,c) plane, 0..4095
  const float* plane = x + (size_t)bc * 16384;
  int t = threadIdx.x;
  float part[16];
  // iter i covers rows [8i,8i+8); thread t reads float4 at row 8i+t/32, col 4*(t%32)
  #pragma unroll
  for (int i = 0; i < 16; ++i) {
    float4 f = *(const float4*)(plane + i * 1024 + t * 4);
    part[i] = f.x + f.y + f.z + f.w;         // lands entirely in col-block (t%32)/2
  }
  __shared__ float lds[256][17];             // +1 pad -> conflict-free
  #pragma unroll
  for (int i = 0; i < 16; ++i) lds[t][i] = part[i];
  __syncthreads();
  // output element s = i*16 + jj ; contributors: threads 32r + 2jj + p
  int i = t >> 4, jj = t & 15;
  float s = 0.f;
  #pragma unroll
  for (int r = 0; r < 8; ++r)
    s += lds[32 * r + 2 * jj][i] + lds[32 * r + 2 * jj + 1][i];
  ws[OFF_V + (size_t)bc * 256 + t] = s * (1.0f / 64.0f);
}

// ---------- t1[m,c] = sum_s v[c,s] psi[k,s,d], softmax over c -> A ----------
__global__ void __launch_bounds__(256) k_psm(const float* __restrict__ psi,
                                             float* __restrict__ ws) {
  int b = blockIdx.y, g = blockIdx.x, t = threadIdx.x;
  int m0 = g * 8;
  __shared__ float pc[8][256];   // psi columns for this m-group
  __shared__ float red[4];
  const float* v = ws + OFF_V + (size_t)b * Cn * Sn;
  #pragma unroll
  for (int mm = 0; mm < 8; ++mm) {
    int m = m0 + mm, k = m / Ln, d = m % Ln;
    pc[mm][t] = psi[(size_t)k * Sn * Ln + (size_t)t * Ln + d];
  }
  __syncthreads();
  float acc[2][8];
  #pragma unroll
  for (int ci = 0; ci < 2; ++ci) {
    const float* vp = v + (size_t)(t + ci * 256) * Sn;
    float a[8] = {0, 0, 0, 0, 0, 0, 0, 0};
    for (int s = 0; s < Sn; s += 4) {
      float4 vv = *(const float4*)(vp + s);
      #pragma unroll
      for (int mm = 0; mm < 8; ++mm)
        a[mm] += vv.x * pc[mm][s] + vv.y * pc[mm][s + 1] +
                 vv.z * pc[mm][s + 2] + vv.w * pc[mm][s + 3];
    }
    #pragma unroll
    for (int mm = 0; mm < 8; ++mm) acc[ci][mm] = a[mm];
  }
  #pragma unroll
  for (int mm = 0; mm < 8; ++mm) {
    float mx = blk_max(fmaxf(acc[0][mm], acc[1][mm]), red);
    float e0 = expf(acc[0][mm] - mx), e1 = expf(acc[1][mm] - mx);
    float inv = 1.0f / blk_sum(e0 + e1, red);
    float* Arow = ws + OFF_A + ((size_t)b * Mn + m0 + mm) * Cn;
    Arow[t] = e0 * inv;
    Arow[t + 256] = e1 * inv;
  }
}

// ---------- z[m,s] = sum_c A[m,c] v[c,s]; also 1/(||z||+eps) and z.wsum ----------
__global__ void __launch_bounds__(256) k_z(float* __restrict__ ws) {
  int b = blockIdx.y, g = blockIdx.x, t = threadIdx.x;
  int m0 = g * 8;
  __shared__ float As[8][512];   // 16 KiB
  __shared__ float red[4];
  const float* v = ws + OFF_V + (size_t)b * Cn * Sn;
  const float* A = ws + OFF_A + (size_t)b * Mn * Cn;
  #pragma unroll
  for (int mm = 0; mm < 8; ++mm) {
    As[mm][t]       = A[(size_t)(m0 + mm) * Cn + t];
    As[mm][t + 256] = A[(size_t)(m0 + mm) * Cn + t + 256];
  }
  __syncthreads();
  float acc[8] = {0, 0, 0, 0, 0, 0, 0, 0};
  for (int c = 0; c < Cn; ++c) {
    float vv = v[(size_t)c * Sn + t];        // coalesced
    #pragma unroll
    for (int mm = 0; mm < 8; ++mm) acc[mm] += As[mm][c] * vv;  // LDS broadcast
  }
  float wsv = ws[OFF_WSUM + t];
  #pragma unroll
  for (int mm = 0; mm < 8; ++mm) {
    int m = m0 + mm;
    ws[OFF_Z + ((size_t)b * Mn + m) * Sn + t] = acc[mm];
    float n2 = blk_sum(acc[mm] * acc[mm], red);
    float zw = blk_sum(acc[mm] * wsv, red);
    if (t == 0) {
      ws[OFF_INV + (size_t)b * Mn + m] = 1.0f / (sqrtf(n2) + 1e-6f);
      ws[OFF_ZW  + (size_t)b * Mn + m] = zw;
    }
  }
}

// ---------- G = softmax_n(zn.zn); zp_w[m] = sum_n G[m,n] zw[n] ----------
__global__ void __launch_bounds__(256) k_g(float* __restrict__ ws) {
  int b = blockIdx.y, g = blockIdx.x, t = threadIdx.x;
  int m0 = g * 8;
  __shared__ float zl[8][256];
  __shared__ float invl[200], zwl[200];
  __shared__ float red[4];
  const float* z = ws + OFF_Z + (size_t)b * Mn * Sn;
  #pragma unroll
  for (int mm = 0; mm < 8; ++mm) zl[mm][t] = z[(size_t)(m0 + mm) * Sn + t];
  if (t < Mn) {
    invl[t] = ws[OFF_INV + (size_t)b * Mn + t];
    zwl[t]  = ws[OFF_ZW  + (size_t)b * Mn + t];
  }
  __syncthreads();
  float dot[8] = {0, 0, 0, 0, 0, 0, 0, 0};
  if (t < Mn) {
    const float* zr = z + (size_t)t * Sn;    // thread t owns row n = t
    for (int s = 0; s < Sn; s += 4) {
      float4 zz = *(const float4*)(zr + s);
      #pragma unroll
      for (int mm = 0; mm < 8; ++mm)
        dot[mm] += zz.x * zl[mm][s] + zz.y * zl[mm][s + 1] +
                   zz.z * zl[mm][s + 2] + zz.w * zl[mm][s + 3];
    }
  }
  #pragma unroll
  for (int mm = 0; mm < 8; ++mm) {
    int m = m0 + mm;
    float val = (t < Mn) ? dot[mm] * invl[m] * invl[t] : -1e30f;
    float mx = blk_max(val, red);
    float e  = (t < Mn) ? expf(val - mx) : 0.f;
    float se  = blk_sum(e, red);
    float sez = blk_sum(e * ((t < Mn) ? zwl[t] : 0.f), red);
    if (t == 0) ws[OFF_ZPW + (size_t)b * Mn + m] = sez / se;
  }
}

// ---------- t2 = v.phi, softmax over d, dot zp_w, + vsum, sigmoid ----------
__global__ void __launch_bounds__(256) k_out(const float* __restrict__ phi,
                                             float* __restrict__ out,
                                             float* __restrict__ ws) {
  int b = blockIdx.y, cg = blockIdx.x, t = threadIdx.x;
  int c0 = cg * 8;
  __shared__ float vl[8][256];
  __shared__ float zpl[200];
  __shared__ float t2l[16][104];
  __shared__ float resl[2][8];
  __shared__ float vsl[8];
  const float* v = ws + OFF_V + ((size_t)b * Cn + c0) * Sn;
  #pragma unroll
  for (int cc = 0; cc < 8; ++cc) vl[cc][t] = v[(size_t)cc * Sn + t];
  if (t < Mn) zpl[t] = ws[OFF_ZPW + (size_t)b * Mn + t];
  __syncthreads();
  int k = t >> 7, d = t & 127;
  int dd = d < Ln ? d : Ln - 1;              // inactive lanes read a valid addr
  const float* pp = phi + (size_t)k * Sn * Ln + dd;
  float acc[8] = {0, 0, 0, 0, 0, 0, 0, 0};
  for (int s = 0; s < Sn; ++s) {
    float p = pp[(size_t)s * Ln];            // coalesced across d
    #pragma unroll
    for (int cc = 0; cc < 8; ++cc) acc[cc] += vl[cc][s] * p;
  }
  if (d < Ln) {
    #pragma unroll
    for (int cc = 0; cc < 8; ++cc) t2l[k * 8 + cc][d] = acc[cc];
  }
  __syncthreads();
  // 16 groups of 16 lanes; group gg = k2*8+cc2 reduces over d (100 entries)
  int gg = t >> 4, l = t & 15;
  int k2 = gg >> 3, cc2 = gg & 7;
  float mx = -1e30f;
  for (int dq = l; dq < Ln; dq += 16) mx = fmaxf(mx, t2l[gg][dq]);
  #pragma unroll
  for (int o = 8; o; o >>= 1) mx = fmaxf(mx, __shfl_xor(mx, o));
  float se = 0.f, sez = 0.f;
  for (int dq = l; dq < Ln; dq += 16) {
    float e = expf(t2l[gg][dq] - mx);
    se += e;
    sez += e * zpl[k2 * Ln + dq];
  }
  #pragma unroll
  for (int o = 8; o; o >>= 1) { se += __shfl_xor(se, o); sez += __shfl_xor(sez, o); }
  float vs = 0.f;
  if (k2 == 0) {                              // k=0 groups also compute vsum[cc]
    for (int i2 = 0; i2 < 16; ++i2) vs += vl[cc2][i2 * 16 + l];
    #pragma unroll
    for (int o = 8; o; o >>= 1) vs += __shfl_xor(vs, o);
    if (l == 0) vsl[cc2] = vs;
  }
  if (l == 0) resl[k2][cc2] = sez / se;
  __syncthreads();
  if (t < 8) {
    float f = (vsl[t] + resl[0][t] + resl[1][t]) * (1.0f / 256.0f);
    out[(size_t)b * Cn + c0 + t] = 1.0f / (1.0f + expf(-f));
  }
}

extern "C" void kernel_launch(void* const* d_in, const int* in_sizes, int n_in,
                              void* d_out, int out_size, void* d_ws, size_t ws_size,
                              hipStream_t stream) {
  const float* x   = (const float*)d_in[0];
  const float* psi = (const float*)d_in[1];
  const float* phi = (const float*)d_in[2];
  const float* ow  = (const float*)d_in[3];
  float* out = (float*)d_out;
  float* ws  = (float*)d_ws;

  hipLaunchKernelGGL(k_wsum, dim3(1),       dim3(256), 0, stream, ow, ws);
  hipLaunchKernelGGL(k_pool, dim3(4096),    dim3(256), 0, stream, x, ws);
  hipLaunchKernelGGL(k_psm,  dim3(25, 8),   dim3(256), 0, stream, psi, ws);
  hipLaunchKernelGGL(k_z,    dim3(25, 8),   dim3(256), 0, stream, ws);
  hipLaunchKernelGGL(k_g,    dim3(25, 8),   dim3(256), 0, stream, ws);
  hipLaunchKernelGGL(k_out,  dim3(64, 8),   dim3(256), 0, stream, phi, out, ws);
}

// Round 2
// 125.799 us; speedup vs baseline: 1.2462x; 1.2462x over previous
//
#include <hip/hip_runtime.h>
#include <math.h>

constexpr int Bn = 8, Cn = 512, Sn = 256, Mn = 200, Ln = 100;

// workspace layout (in floats)
constexpr size_t OFF_V    = 0;                                // [B*C*S]
constexpr size_t OFF_Z    = OFF_V   + (size_t)Bn*Cn*Sn;       // [B*M*S]
constexpr size_t OFF_INV  = OFF_Z   + (size_t)Bn*Mn*Sn;       // [B*M]
constexpr size_t OFF_ZW   = OFF_INV + (size_t)Bn*Mn;          // [B*M]
constexpr size_t OFF_ZPW  = OFF_ZW  + (size_t)Bn*Mn;          // [B*M]
constexpr size_t OFF_WSUM = OFF_ZPW + (size_t)Bn*Mn;          // [S]

// ---------- vectorized block reductions (NW = waves per block) ----------
template<int NW>
__device__ __forceinline__ float4 blk_max_f4(float4 x, float4* red) {
  #pragma unroll
  for (int o = 32; o; o >>= 1) {
    x.x = fmaxf(x.x, __shfl_xor(x.x, o));
    x.y = fmaxf(x.y, __shfl_xor(x.y, o));
    x.z = fmaxf(x.z, __shfl_xor(x.z, o));
    x.w = fmaxf(x.w, __shfl_xor(x.w, o));
  }
  __syncthreads();
  if ((threadIdx.x & 63) == 0) red[threadIdx.x >> 6] = x;
  __syncthreads();
  float4 r = red[0];
  #pragma unroll
  for (int w = 1; w < NW; ++w) {
    r.x = fmaxf(r.x, red[w].x); r.y = fmaxf(r.y, red[w].y);
    r.z = fmaxf(r.z, red[w].z); r.w = fmaxf(r.w, red[w].w);
  }
  return r;
}
template<int NW>
__device__ __forceinline__ float4 blk_sum_f4(float4 x, float4* red) {
  #pragma unroll
  for (int o = 32; o; o >>= 1) {
    x.x += __shfl_xor(x.x, o); x.y += __shfl_xor(x.y, o);
    x.z += __shfl_xor(x.z, o); x.w += __shfl_xor(x.w, o);
  }
  __syncthreads();
  if ((threadIdx.x & 63) == 0) red[threadIdx.x >> 6] = x;
  __syncthreads();
  float4 r = red[0];
  #pragma unroll
  for (int w = 1; w < NW; ++w) {
    r.x += red[w].x; r.y += red[w].y; r.z += red[w].z; r.w += red[w].w;
  }
  return r;
}

// ---------- 8x8 block-mean pool + (block 4096) wsum ----------
__global__ void __launch_bounds__(256) k_pool(const float* __restrict__ x,
                                              const float* __restrict__ ow,
                                              float* __restrict__ ws) {
  int t = threadIdx.x;
  if (blockIdx.x == 4096) {                  // wsum[s] = sum_t out_w[s,t]
    const float* row = ow + (size_t)t * Sn;
    float s = 0.f;
    for (int j = 0; j < Sn; j += 4) {
      float4 f = *(const float4*)(row + j);
      s += f.x + f.y + f.z + f.w;
    }
    ws[OFF_WSUM + t] = s;
    return;
  }
  int bc = blockIdx.x;                       // (b,c) plane, 0..4095
  const float* plane = x + (size_t)bc * 16384;
  float part[16];
  #pragma unroll
  for (int i = 0; i < 16; ++i) {
    float4 f = *(const float4*)(plane + i * 1024 + t * 4);
    part[i] = f.x + f.y + f.z + f.w;
  }
  __shared__ float lds[256][17];
  #pragma unroll
  for (int i = 0; i < 16; ++i) lds[t][i] = part[i];
  __syncthreads();
  int i = t >> 4, jj = t & 15;
  float s = 0.f;
  #pragma unroll
  for (int r = 0; r < 8; ++r)
    s += lds[32 * r + 2 * jj][i] + lds[32 * r + 2 * jj + 1][i];
  ws[OFF_V + (size_t)bc * 256 + t] = s * (1.0f / 64.0f);
}

// ---------- fused: t1 = v.psi -> softmax_c -> A (LDS) -> z = A.v, ||z||, z.wsum ----------
__global__ void __launch_bounds__(512) k_psz(const float* __restrict__ psi,
                                             float* __restrict__ ws) {
  int b = blockIdx.y, g = blockIdx.x, t = threadIdx.x;
  int m0 = g * 8;
  __shared__ __align__(16) float pc[8][256];       // psi columns
  __shared__ __align__(16) float As[8][512];       // softmaxed affinity
  __shared__ __align__(16) float zpart[2][8][256];
  __shared__ float4 red4[8];
  const float* v = ws + OFF_V + (size_t)b * Cn * Sn;

  for (int e = t; e < 8 * 256; e += 512) {
    int mm = e >> 8, s = e & 255;
    int m = m0 + mm, k = m / Ln, d = m % Ln;
    pc[mm][s] = psi[(size_t)k * Sn * Ln + (size_t)s * Ln + d];
  }
  __syncthreads();

  // phase 1: thread t owns channel c = t
  float acc[8] = {0, 0, 0, 0, 0, 0, 0, 0};
  {
    const float* vp = v + (size_t)t * Sn;
    for (int s = 0; s < Sn; s += 4) {
      float4 vv = *(const float4*)(vp + s);
      #pragma unroll
      for (int mm = 0; mm < 8; ++mm) {
        float4 p = *(const float4*)&pc[mm][s];
        acc[mm] += vv.x * p.x + vv.y * p.y + vv.z * p.z + vv.w * p.w;
      }
    }
  }
  #pragma unroll
  for (int q = 0; q < 2; ++q) {
    float4 a = make_float4(acc[4*q], acc[4*q+1], acc[4*q+2], acc[4*q+3]);
    float4 mx = blk_max_f4<8>(a, red4);
    float4 e;
    e.x = expf(a.x - mx.x); e.y = expf(a.y - mx.y);
    e.z = expf(a.z - mx.z); e.w = expf(a.w - mx.w);
    float4 se = blk_sum_f4<8>(e, red4);
    As[4*q+0][t] = e.x / se.x;
    As[4*q+1][t] = e.y / se.y;
    As[4*q+2][t] = e.z / se.z;
    As[4*q+3][t] = e.w / se.w;
  }
  __syncthreads();

  // phase 2: z[m, s2] ; thread = (h = c-half, s2)
  int h = t >> 8, s2 = t & 255;
  float a2[8] = {0, 0, 0, 0, 0, 0, 0, 0};
  const float* vb = v + (size_t)h * 256 * Sn;
  for (int c = 0; c < 256; c += 4) {
    float v0 = vb[(size_t)(c + 0) * Sn + s2];
    float v1 = vb[(size_t)(c + 1) * Sn + s2];
    float v2 = vb[(size_t)(c + 2) * Sn + s2];
    float v3 = vb[(size_t)(c + 3) * Sn + s2];
    #pragma unroll
    for (int mm = 0; mm < 8; ++mm) {
      float4 aa = *(const float4*)&As[mm][h * 256 + c];
      a2[mm] += aa.x * v0 + aa.y * v1 + aa.z * v2 + aa.w * v3;
    }
  }
  #pragma unroll
  for (int mm = 0; mm < 8; ++mm) zpart[h][mm][s2] = a2[mm];
  __syncthreads();

  float zv[8] = {0, 0, 0, 0, 0, 0, 0, 0};
  float wsv = 0.f;
  if (t < 256) {
    wsv = ws[OFF_WSUM + t];
    float* zo = ws + OFF_Z + ((size_t)b * Mn + m0) * Sn;
    #pragma unroll
    for (int mm = 0; mm < 8; ++mm) {
      zv[mm] = zpart[0][mm][t] + zpart[1][mm][t];
      zo[(size_t)mm * Sn + t] = zv[mm];
    }
  }
  #pragma unroll
  for (int q = 0; q < 2; ++q) {
    float4 sq = make_float4(zv[4*q]*zv[4*q], zv[4*q+1]*zv[4*q+1],
                            zv[4*q+2]*zv[4*q+2], zv[4*q+3]*zv[4*q+3]);
    float4 n2 = blk_sum_f4<8>(sq, red4);
    float4 zw = blk_sum_f4<8>(make_float4(zv[4*q]*wsv, zv[4*q+1]*wsv,
                                          zv[4*q+2]*wsv, zv[4*q+3]*wsv), red4);
    if (t == 0) {
      float* inv = ws + OFF_INV + (size_t)b * Mn + m0 + 4*q;
      float* zwp = ws + OFF_ZW  + (size_t)b * Mn + m0 + 4*q;
      inv[0] = 1.0f / (sqrtf(n2.x) + 1e-6f); zwp[0] = zw.x;
      inv[1] = 1.0f / (sqrtf(n2.y) + 1e-6f); zwp[1] = zw.y;
      inv[2] = 1.0f / (sqrtf(n2.z) + 1e-6f); zwp[2] = zw.z;
      inv[3] = 1.0f / (sqrtf(n2.w) + 1e-6f); zwp[3] = zw.w;
    }
  }
}

// ---------- G = softmax_n(zn.zn); zp_w[m] = sum_n G[m,n] zw[n] ----------
__global__ void __launch_bounds__(256) k_g(float* __restrict__ ws) {
  int b = blockIdx.y, g = blockIdx.x, t = threadIdx.x;
  int m0 = g * 4;
  __shared__ __align__(16) float zl[4][256];
  __shared__ float invl[200], zwl[200];
  __shared__ float4 red4[4];
  const float* z = ws + OFF_Z + (size_t)b * Mn * Sn;
  #pragma unroll
  for (int mm = 0; mm < 4; ++mm) zl[mm][t] = z[(size_t)(m0 + mm) * Sn + t];
  if (t < Mn) {
    invl[t] = ws[OFF_INV + (size_t)b * Mn + t];
    zwl[t]  = ws[OFF_ZW  + (size_t)b * Mn + t];
  }
  __syncthreads();
  bool act = t < Mn;
  float dot[4] = {0, 0, 0, 0};
  if (act) {
    const float* zr = z + (size_t)t * Sn;
    for (int s = 0; s < Sn; s += 4) {
      float4 zz = *(const float4*)(zr + s);
      #pragma unroll
      for (int mm = 0; mm < 4; ++mm) {
        float4 zl4 = *(const float4*)&zl[mm][s];
        dot[mm] += zz.x * zl4.x + zz.y * zl4.y + zz.z * zl4.z + zz.w * zl4.w;
      }
    }
  }
  float4 val;
  val.x = act ? dot[0] * invl[m0 + 0] * invl[t] : -1e30f;
  val.y = act ? dot[1] * invl[m0 + 1] * invl[t] : -1e30f;
  val.z = act ? dot[2] * invl[m0 + 2] * invl[t] : -1e30f;
  val.w = act ? dot[3] * invl[m0 + 3] * invl[t] : -1e30f;
  float4 mx = blk_max_f4<4>(val, red4);
  float4 e;
  e.x = act ? expf(val.x - mx.x) : 0.f;
  e.y = act ? expf(val.y - mx.y) : 0.f;
  e.z = act ? expf(val.z - mx.z) : 0.f;
  e.w = act ? expf(val.w - mx.w) : 0.f;
  float4 se = blk_sum_f4<4>(e, red4);
  float zwn = act ? zwl[t] : 0.f;
  float4 sez = blk_sum_f4<4>(make_float4(e.x*zwn, e.y*zwn, e.z*zwn, e.w*zwn), red4);
  if (t == 0) {
    float* zp = ws + OFF_ZPW + (size_t)b * Mn + m0;
    zp[0] = sez.x / se.x; zp[1] = sez.y / se.y;
    zp[2] = sez.z / se.z; zp[3] = sez.w / se.w;
  }
}

// ---------- t2 = v.phi, softmax over d, dot zp_w, + vsum, sigmoid ----------
__global__ void __launch_bounds__(256) k_out(const float* __restrict__ phi,
                                             float* __restrict__ out,
                                             float* __restrict__ ws) {
  int b = blockIdx.y, cg = blockIdx.x, t = threadIdx.x;
  int c0 = cg * 8;
  __shared__ __align__(16) float vl[8][256];
  __shared__ float zpl[200];
  __shared__ float t2l[16][104];
  __shared__ float resl[2][8];
  __shared__ float vsl[8];
  const float* v = ws + OFF_V + ((size_t)b * Cn + c0) * Sn;
  #pragma unroll
  for (int cc = 0; cc < 8; ++cc) vl[cc][t] = v[(size_t)cc * Sn + t];
  if (t < Mn) zpl[t] = ws[OFF_ZPW + (size_t)b * Mn + t];
  __syncthreads();
  int k = t >> 7, d = t & 127;
  int dd = d < Ln ? d : Ln - 1;
  const float* pp = phi + (size_t)k * Sn * Ln + dd;
  float acc[8] = {0, 0, 0, 0, 0, 0, 0, 0};
  for (int s = 0; s < Sn; s += 4) {
    float p0 = pp[(size_t)(s + 0) * Ln];
    float p1 = pp[(size_t)(s + 1) * Ln];
    float p2 = pp[(size_t)(s + 2) * Ln];
    float p3 = pp[(size_t)(s + 3) * Ln];
    #pragma unroll
    for (int cc = 0; cc < 8; ++cc) {
      float4 vv = *(const float4*)&vl[cc][s];
      acc[cc] += vv.x * p0 + vv.y * p1 + vv.z * p2 + vv.w * p3;
    }
  }
  if (d < Ln) {
    #pragma unroll
    for (int cc = 0; cc < 8; ++cc) t2l[k * 8 + cc][d] = acc[cc];
  }
  __syncthreads();
  int gg = t >> 4, l = t & 15;
  int k2 = gg >> 3, cc2 = gg & 7;
  float mx = -1e30f;
  for (int dq = l; dq < Ln; dq += 16) mx = fmaxf(mx, t2l[gg][dq]);
  #pragma unroll
  for (int o = 8; o; o >>= 1) mx = fmaxf(mx, __shfl_xor(mx, o));
  float se = 0.f, sez = 0.f;
  for (int dq = l; dq < Ln; dq += 16) {
    float e = expf(t2l[gg][dq] - mx);
    se += e;
    sez += e * zpl[k2 * Ln + dq];
  }
  #pragma unroll
  for (int o = 8; o; o >>= 1) { se += __shfl_xor(se, o); sez += __shfl_xor(sez, o); }
  float vs = 0.f;
  if (k2 == 0) {
    for (int i2 = 0; i2 < 16; ++i2) vs += vl[cc2][i2 * 16 + l];
    #pragma unroll
    for (int o = 8; o; o >>= 1) vs += __shfl_xor(vs, o);
    if (l == 0) vsl[cc2] = vs;
  }
  if (l == 0) resl[k2][cc2] = sez / se;
  __syncthreads();
  if (t < 8) {
    float f = (vsl[t] + resl[0][t] + resl[1][t]) * (1.0f / 256.0f);
    out[(size_t)b * Cn + c0 + t] = 1.0f / (1.0f + expf(-f));
  }
}

extern "C" void kernel_launch(void* const* d_in, const int* in_sizes, int n_in,
                              void* d_out, int out_size, void* d_ws, size_t ws_size,
                              hipStream_t stream) {
  const float* x   = (const float*)d_in[0];
  const float* psi = (const float*)d_in[1];
  const float* phi = (const float*)d_in[2];
  const float* ow  = (const float*)d_in[3];
  float* out = (float*)d_out;
  float* ws  = (float*)d_ws;

  hipLaunchKernelGGL(k_pool, dim3(4097),   dim3(256), 0, stream, x, ow, ws);
  hipLaunchKernelGGL(k_psz,  dim3(25, 8),  dim3(512), 0, stream, psi, ws);
  hipLaunchKernelGGL(k_g,    dim3(50, 8),  dim3(256), 0, stream, ws);
  hipLaunchKernelGGL(k_out,  dim3(64, 8),  dim3(256), 0, stream, phi, out, ws);
}